// Round 5
// baseline (5324.037 us; speedup 1.0000x reference)
//
#include <hip/hip_runtime.h>
#include <hip/hip_bf16.h>

#define S_ 160
#define B_ 64
#define H_ 1024
#define E_ 512
#define V_ 64
#define T_ 16
#define H4_ 4096

__device__ __forceinline__ float sigm(float x) { return 1.f / (1.f + expf(-x)); }

// ---------------------------------------------------------------------------
// GEMM C[M,N] = A[M,K] @ Bm[N,K]^T. 64x64 tile, BK=16, 256 thr, 4x4 acc.
// Direct variant (+bias/bias2/addend) and split-K partial variant.
// ---------------------------------------------------------------------------
__global__ __launch_bounds__(256) void gemm_direct(
    const float* __restrict__ A, const float* __restrict__ Bm,
    const float* __restrict__ bias, const float* __restrict__ bias2,
    const float* __restrict__ addend, float* __restrict__ Cd, int M, int N, int K)
{
    __shared__ float As[64][17];
    __shared__ float Bs[64][17];
    const int bn = blockIdx.x, bm = blockIdx.y;
    const int tid = threadIdx.x;
    const int lr = tid >> 2, lc = (tid & 3) << 2;
    const int tx = tid & 15, ty = tid >> 4;
    const float* Ap = A + (size_t)(bm * 64 + lr) * K + lc;
    const float* Bp = Bm + (size_t)(bn * 64 + lr) * K + lc;
    float acc[4][4] = {};
    for (int k0 = 0; k0 < K; k0 += 16) {
        float4 av = *(const float4*)(Ap + k0);
        float4 bv = *(const float4*)(Bp + k0);
        As[lr][lc] = av.x; As[lr][lc + 1] = av.y; As[lr][lc + 2] = av.z; As[lr][lc + 3] = av.w;
        Bs[lr][lc] = bv.x; Bs[lr][lc + 1] = bv.y; Bs[lr][lc + 2] = bv.z; Bs[lr][lc + 3] = bv.w;
        __syncthreads();
#pragma unroll
        for (int kk = 0; kk < 16; ++kk) {
            float a[4], b[4];
#pragma unroll
            for (int i = 0; i < 4; ++i) a[i] = As[ty * 4 + i][kk];
#pragma unroll
            for (int j = 0; j < 4; ++j) b[j] = Bs[tx * 4 + j][kk];
#pragma unroll
            for (int i = 0; i < 4; ++i)
#pragma unroll
                for (int j = 0; j < 4; ++j) acc[i][j] = fmaf(a[i], b[j], acc[i][j]);
        }
        __syncthreads();
    }
#pragma unroll
    for (int i = 0; i < 4; ++i) {
        int row = bm * 64 + ty * 4 + i;
#pragma unroll
        for (int j = 0; j < 4; ++j) {
            int col = bn * 64 + tx * 4 + j;
            float v = acc[i][j];
            if (bias)   v += bias[col];
            if (bias2)  v += bias2[col];
            if (addend) v += addend[(size_t)row * N + col];
            Cd[(size_t)row * N + col] = v;
        }
    }
}

__global__ __launch_bounds__(256) void gemm_part(
    const float* __restrict__ A, const float* __restrict__ Bm,
    float* __restrict__ Cpart, int M, int N, int K)
{
    __shared__ float As[64][17];
    __shared__ float Bs[64][17];
    const int bn = blockIdx.x, bm = blockIdx.y, kz = blockIdx.z, KS = gridDim.z;
    const int tid = threadIdx.x;
    const int lr = tid >> 2, lc = (tid & 3) << 2;
    const int tx = tid & 15, ty = tid >> 4;
    const int kLen = K / KS, k0base = kz * kLen;
    const float* Ap = A + (size_t)(bm * 64 + lr) * K + k0base + lc;
    const float* Bp = Bm + (size_t)(bn * 64 + lr) * K + k0base + lc;
    float acc[4][4] = {};
    for (int k0 = 0; k0 < kLen; k0 += 16) {
        float4 av = *(const float4*)(Ap + k0);
        float4 bv = *(const float4*)(Bp + k0);
        As[lr][lc] = av.x; As[lr][lc + 1] = av.y; As[lr][lc + 2] = av.z; As[lr][lc + 3] = av.w;
        Bs[lr][lc] = bv.x; Bs[lr][lc + 1] = bv.y; Bs[lr][lc + 2] = bv.z; Bs[lr][lc + 3] = bv.w;
        __syncthreads();
#pragma unroll
        for (int kk = 0; kk < 16; ++kk) {
            float a[4], b[4];
#pragma unroll
            for (int i = 0; i < 4; ++i) a[i] = As[ty * 4 + i][kk];
#pragma unroll
            for (int j = 0; j < 4; ++j) b[j] = Bs[tx * 4 + j][kk];
#pragma unroll
            for (int i = 0; i < 4; ++i)
#pragma unroll
                for (int j = 0; j < 4; ++j) acc[i][j] = fmaf(a[i], b[j], acc[i][j]);
        }
        __syncthreads();
    }
    float* Cp = Cpart + (size_t)kz * M * N;
#pragma unroll
    for (int i = 0; i < 4; ++i) {
        int row = bm * 64 + ty * 4 + i;
#pragma unroll
        for (int j = 0; j < 4; ++j) {
            int col = bn * 64 + tx * 4 + j;
            Cp[(size_t)row * N + col] = acc[i][j];
        }
    }
}

__global__ void reduce_partials(const float* __restrict__ Cpart, int KS,
                                const float* __restrict__ bias,
                                const float* __restrict__ bias2,
                                const float* __restrict__ addend,
                                float* __restrict__ C, int MN, int N)
{
    int idx = blockIdx.x * 256 + threadIdx.x;
    if (idx >= MN) return;
    float v = 0.f;
    for (int z = 0; z < KS; ++z) v += Cpart[(size_t)z * MN + idx];
    int col = idx % N;
    if (bias)  v += bias[col];
    if (bias2) v += bias2[col];
    if (addend) v += addend[idx];
    C[idx] = v;
}

__global__ void init_k(const float* __restrict__ tok_embed, float* __restrict__ cur_emb,
                       float* __restrict__ negent_acc, float* __restrict__ logp_acc)
{
    int i = blockIdx.x * 256 + threadIdx.x;
    if (i < B_ * E_) cur_emb[i] = tok_embed[i % E_];
    if (i < B_) { negent_acc[i] = 0.f; logp_acc[i] = 0.f; }
}

__global__ void lstm_cell_k(const float* __restrict__ gates, const float* __restrict__ c0,
                            float* __restrict__ outh)
{
    int idx = blockIdx.x * 256 + threadIdx.x;   // B_*H_
    int b = idx >> 10, h = idx & (H_ - 1);
    const float* g = gates + (size_t)b * H4_;
    float gi = g[h], gf = g[H_ + h], gg = g[2 * H_ + h], go = g[3 * H_ + h];
    float c = sigm(gf) * c0[idx] + sigm(gi) * tanhf(gg);
    outh[idx] = sigm(go) * tanhf(c);
}

// Shared epilogue: masked softmax over sc[S_], write attn map (f32), context.
__device__ __forceinline__ void attn_softmax_context(
    float* sc, const float* __restrict__ enc_out, int b,
    float* __restrict__ context, float* __restrict__ out_attn, int t)
{
    const int wave = threadIdx.x >> 6, lane = threadIdx.x & 63;
    if (wave == 0) {
        float m = -1e30f;
        for (int s = lane; s < S_; s += 64) m = fmaxf(m, sc[s]);
        for (int d = 32; d; d >>= 1) m = fmaxf(m, __shfl_xor(m, d));
        float sum = 0.f;
        for (int s = lane; s < S_; s += 64) { float e = expf(sc[s] - m); sc[s] = e; sum += e; }
        for (int d = 32; d; d >>= 1) sum += __shfl_xor(sum, d);
        float inv = 1.f / sum;
        for (int s = lane; s < S_; s += 64) {
            float p = sc[s] * inv;
            sc[s] = p;
            out_attn[((size_t)b * T_ + t) * S_ + s] = p;
        }
    }
    __syncthreads();
    for (int h0 = 0; h0 < H_; h0 += 256) {
        int h = h0 + threadIdx.x;
        float acc = 0.f;
        for (int s = 0; s < S_; ++s) acc += sc[s] * enc_out[((size_t)s * B_ + b) * H_ + h];
        context[b * H_ + h] = acc;
    }
}

// Tier 1: enc_t precomputed in f32.
__global__ __launch_bounds__(256) void attn_step_k(
    const float* __restrict__ enc_t, const float* __restrict__ enc_out,
    const float* __restrict__ dec_t, const float* __restrict__ attn_W,
    const float* __restrict__ attn_b, const int* __restrict__ lens,
    float* __restrict__ context, float* __restrict__ out_attn, int t)
{
    __shared__ float decs[H_];
    __shared__ float aw[H_];
    __shared__ float sc[S_];
    const int b = blockIdx.x;
    for (int i = threadIdx.x; i < H_; i += 256) {
        decs[i] = dec_t[b * H_ + i];
        aw[i] = attn_W[i];
    }
    __syncthreads();
    const int wave = threadIdx.x >> 6, lane = threadIdx.x & 63;
    const int len = lens[b];
    const float ab = attn_b[0];
    for (int s = wave; s < S_; s += 4) {
        float acc = 0.f;
        const float* ep = enc_t + ((size_t)s * B_ + b) * H_;
#pragma unroll
        for (int it = 0; it < H_ / 64; ++it) {
            int h = lane + it * 64;
            acc += aw[h] * tanhf(ep[h] + decs[h]);
        }
        for (int d = 32; d; d >>= 1) acc += __shfl_xor(acc, d);
        if (lane == 0) sc[s] = (s < len) ? (acc + ab) : -1e9f;
    }
    __syncthreads();
    attn_softmax_context(sc, enc_out, b, context, out_attn, t);
}

// Tiers 3/4: recompute enc_out @ enc_W^T rows on the fly (small ws fallback).
__global__ __launch_bounds__(256) void attn_fused_k(
    const float* __restrict__ enc_out, const float* __restrict__ enc_W,
    const float* __restrict__ enc_b,
    const float* __restrict__ dec_t, const float* __restrict__ attn_W,
    const float* __restrict__ attn_b, const int* __restrict__ lens,
    float* __restrict__ context, float* __restrict__ out_attn, int t)
{
    __shared__ float decs[H_];
    __shared__ float aw[H_];
    __shared__ float encsh[H_];
    __shared__ float sc[S_];
    __shared__ float wsum[4];
    const int b = blockIdx.x;
    for (int i = threadIdx.x; i < H_; i += 256) {
        decs[i] = dec_t[b * H_ + i] + enc_b[i];
        aw[i] = attn_W[i];
    }
    const int wave = threadIdx.x >> 6, lane = threadIdx.x & 63;
    const int len = lens[b];
    const float ab = attn_b[0];
    for (int s = 0; s < S_; ++s) {
        __syncthreads();
        for (int i = threadIdx.x; i < H_; i += 256)
            encsh[i] = enc_out[((size_t)s * B_ + b) * H_ + i];
        __syncthreads();
        float part = 0.f;
#pragma unroll
        for (int kk = 0; kk < 4; ++kk) {
            int k = threadIdx.x * 4 + kk;
            const float* wr = enc_W + (size_t)k * H_;
            float dot = 0.f;
            for (int h = 0; h < H_; h += 4) {
                float4 wv = *(const float4*)(wr + h);
                dot += wv.x * encsh[h] + wv.y * encsh[h + 1] +
                       wv.z * encsh[h + 2] + wv.w * encsh[h + 3];
            }
            part += aw[k] * tanhf(dot + decs[k]);
        }
        for (int d = 32; d; d >>= 1) part += __shfl_xor(part, d);
        if (lane == 0) wsum[wave] = part;
        __syncthreads();
        if (threadIdx.x == 0) {
            float v = wsum[0] + wsum[1] + wsum[2] + wsum[3] + ab;
            sc[s] = (s < len) ? v : -1e9f;
        }
    }
    __syncthreads();
    attn_softmax_context(sc, enc_out, b, context, out_attn, t);
}

__global__ __launch_bounds__(256) void out_step_k(
    const float* __restrict__ context, const float* __restrict__ out_h,
    const float* __restrict__ out_W, const float* __restrict__ out_b,
    const float* __restrict__ embed, float* __restrict__ cur_emb,
    float* __restrict__ negent_acc, float* __restrict__ logp_acc,
    float* __restrict__ out_toks, int t)
{
    __shared__ float comb[2 * H_];
    __shared__ float lg[V_];
    __shared__ int tok_s;
    const int b = blockIdx.x;
    for (int i = threadIdx.x; i < H_; i += 256) {
        comb[i] = context[b * H_ + i];
        comb[H_ + i] = out_h[b * H_ + i];
    }
    __syncthreads();
    const int wave = threadIdx.x >> 6, lane = threadIdx.x & 63;
    for (int v = wave * 16; v < wave * 16 + 16; ++v) {
        float acc = 0.f;
        const float* w = out_W + (size_t)v * (2 * H_);
#pragma unroll
        for (int j = 0; j < (2 * H_) / 64; ++j)
            acc += comb[lane + j * 64] * w[lane + j * 64];
        for (int d = 32; d; d >>= 1) acc += __shfl_xor(acc, d);
        if (lane == 0) lg[v] = acc + out_b[v];
    }
    __syncthreads();
    if (wave == 0) {
        float x = lg[lane];
        float m = x;
        for (int d = 32; d; d >>= 1) m = fmaxf(m, __shfl_xor(m, d));
        float e = expf(x - m);
        float s = e;
        for (int d = 32; d; d >>= 1) s += __shfl_xor(s, d);
        float p = e / s;
        float ps = p;
        for (int d = 32; d; d >>= 1) ps += __shfl_xor(ps, d);
        p = p / ps;   // reference renormalizes
        float bv = p; int bi = lane;
        for (int d = 32; d; d >>= 1) {
            float ov = __shfl_xor(bv, d); int oi = __shfl_xor(bi, d);
            if (ov > bv || (ov == bv && oi < bi)) { bv = ov; bi = oi; }
        }
        float ne = p * logf(p + 1e-6f);
        for (int d = 32; d; d >>= 1) ne += __shfl_xor(ne, d);
        float ptok = __shfl(p, bi);
        if (lane == 0) {
            out_toks[t * B_ + b] = (float)bi;
            negent_acc[b] += ne;
            logp_acc[b] += logf(ptok + 1e-6f);
            tok_s = bi;
        }
    }
    __syncthreads();
    const int tok = tok_s;
    for (int i = threadIdx.x; i < E_; i += 256)
        cur_emb[b * E_ + i] = embed[(size_t)tok * E_ + i];
}

__global__ void final_k(const float* __restrict__ negent_acc, const float* __restrict__ logp_acc,
                        float* __restrict__ out)
{
    int b = threadIdx.x;   // 64
    out[T_ * B_ + B_ * T_ * S_ + b] = negent_acc[b];
    out[T_ * B_ + B_ * T_ * S_ + B_ + b] = logp_acc[b];
}

extern "C" void kernel_launch(void* const* d_in, const int* in_sizes, int n_in,
                              void* d_out, int out_size, void* d_ws, size_t ws_size,
                              hipStream_t stream) {
    const float* enc_h0   = (const float*)d_in[0];
    const float* enc_c0   = (const float*)d_in[1];
    const float* enc_out  = (const float*)d_in[2];
    const int*   lens     = (const int*)d_in[3];
    const float* tok_emb  = (const float*)d_in[4];
    const float* embed    = (const float*)d_in[5];
    const float* W_ih     = (const float*)d_in[6];
    const float* W_hh     = (const float*)d_in[7];
    const float* b_ih     = (const float*)d_in[8];
    const float* b_hh     = (const float*)d_in[9];
    const float* out_W    = (const float*)d_in[10];
    const float* out_b    = (const float*)d_in[11];
    const float* enc_W    = (const float*)d_in[12];
    const float* enc_b    = (const float*)d_in[13];
    const float* dec_W    = (const float*)d_in[14];
    const float* dec_b    = (const float*)d_in[15];
    const float* attn_W   = (const float*)d_in[16];
    const float* attn_b   = (const float*)d_in[17];
    float* out = (float*)d_out;   // f32 output: tokens | attn maps | negent | logp

    // ---- ws layout: small buffers first, everything bounded by ws_size ----
    float* ws = (float*)d_ws;
    float* hh_gates   = ws;                        // 262144 f
    float* gates      = hh_gates + B_ * H4_;       // 262144 f
    float* out_h      = gates + B_ * H4_;          // 65536 f
    float* dec_t      = out_h + B_ * H_;           // 65536 f
    float* context    = dec_t + B_ * H_;           // 65536 f
    float* negent_acc = context + B_ * H_;         // 64 f
    float* logp_acc   = negent_acc + B_;           // 64 f
    float* cur_emb    = logp_acc + B_;             // 32768 f
    float* part       = cur_emb + B_ * E_;         // 753,792 f .. +1,048,576 f
    float* enc_tf     = part + (size_t)4 * B_ * H4_;  // 1,802,368 f .. +10,485,760 f

    // Tier on ws_size (constant across calls -> deterministic, capture-safe).
    // tier1: (1,802,368 + 10,485,760) * 4 = 49,152,512 B
    // tier3: 1,802,368 * 4               =  7,209,472 B
    // tier4: 753,792 * 4 + 1*B*4H*4      =  4,063,232 B
    int tier;
    if      (ws_size >= 49152512u) tier = 1;
    else if (ws_size >=  7209472u) tier = 3;
    else                           tier = 4;
    const int splitk = (tier <= 3);

    init_k<<<(B_ * E_ + 255) / 256, 256, 0, stream>>>(tok_emb, cur_emb, negent_acc, logp_acc);

    // hh_gates = h0 @ W_hh^T + b_ih + b_hh (step-invariant)
    if (splitk) {
        gemm_part<<<dim3(H4_ / 64, 1, 4), 256, 0, stream>>>(enc_h0, W_hh, part, B_, H4_, H_);
        reduce_partials<<<(B_ * H4_ + 255) / 256, 256, 0, stream>>>(
            part, 4, b_ih, b_hh, nullptr, hh_gates, B_ * H4_, H4_);
    } else {
        gemm_direct<<<dim3(H4_ / 64, 1, 1), 256, 0, stream>>>(
            enc_h0, W_hh, b_ih, b_hh, nullptr, hh_gates, B_, H4_, H_);
    }

    // enc_t = encoder_outputs @ enc_W^T + enc_b (tier 1 only)
    if (tier == 1)
        gemm_direct<<<dim3(H_ / 64, (S_ * B_) / 64, 1), 256, 0, stream>>>(
            enc_out, enc_W, enc_b, nullptr, nullptr, enc_tf, S_ * B_, H_, H_);

    for (int t = 0; t < T_; ++t) {
        // gates = cur_emb @ W_ih^T + hh_gates
        if (splitk) {
            gemm_part<<<dim3(H4_ / 64, 1, 4), 256, 0, stream>>>(cur_emb, W_ih, part, B_, H4_, E_);
            reduce_partials<<<(B_ * H4_ + 255) / 256, 256, 0, stream>>>(
                part, 4, nullptr, nullptr, hh_gates, gates, B_ * H4_, H4_);
        } else {
            gemm_direct<<<dim3(H4_ / 64, 1, 1), 256, 0, stream>>>(
                cur_emb, W_ih, nullptr, nullptr, hh_gates, gates, B_, H4_, E_);
        }
        lstm_cell_k<<<(B_ * H_) / 256, 256, 0, stream>>>(gates, enc_c0, out_h);

        // dec_t = out_h @ dec_W^T + dec_b
        if (splitk) {
            gemm_part<<<dim3(H_ / 64, 1, 8), 256, 0, stream>>>(out_h, dec_W, part, B_, H_, H_);
            reduce_partials<<<(B_ * H_ + 255) / 256, 256, 0, stream>>>(
                part, 8, dec_b, nullptr, nullptr, dec_t, B_ * H_, H_);
        } else {
            gemm_direct<<<dim3(H_ / 64, 1, 1), 256, 0, stream>>>(
                out_h, dec_W, dec_b, nullptr, nullptr, dec_t, B_, H_, H_);
        }

        if (tier == 1)
            attn_step_k<<<B_, 256, 0, stream>>>(enc_tf, enc_out, dec_t, attn_W, attn_b,
                                                lens, context, out + T_ * B_, t);
        else
            attn_fused_k<<<B_, 256, 0, stream>>>(enc_out, enc_W, enc_b, dec_t, attn_W,
                                                 attn_b, lens, context, out + T_ * B_, t);

        out_step_k<<<B_, 256, 0, stream>>>(context, out_h, out_W, out_b, embed, cur_emb,
                                           negent_acc, logp_acc, out, t);
    }
    final_k<<<1, B_, 0, stream>>>(negent_acc, logp_acc, out);
}

// Round 7
// 2667.544 us; speedup vs baseline: 1.9959x; 1.9959x over previous
//
#include <hip/hip_runtime.h>

#define S_ 160
#define B_ 64
#define H_ 1024
#define E_ 512
#define V_ 64
#define T_ 16
#define H4_ 4096

__device__ __forceinline__ float sigm(float x) { return 1.f / (1.f + expf(-x)); }

// ---------------------------------------------------------------------------
// enc_t = enc_out @ enc_W^T + enc_b.  128x128 tile, BK=16, 8x8 acc/thread.
// LDS stored [k][row] so fragment loads are float4 (4 FMA per LDS element).
// ---------------------------------------------------------------------------
__global__ __launch_bounds__(256) void gemm_bt_128(
    const float* __restrict__ A, const float* __restrict__ Bm,
    const float* __restrict__ bias, float* __restrict__ Cd,
    int M, int N, int K)
{
    __shared__ float As[16][132];
    __shared__ float Bs[16][132];
    const int bn = blockIdx.x, bm = blockIdx.y;
    const int tid = threadIdx.x;
    const int lr = tid >> 1, lk = (tid & 1) * 8;
    const int tx = (tid & 15) * 8, ty = (tid >> 4) * 8;
    const float* Ap = A + (size_t)(bm * 128 + lr) * K + lk;
    const float* Bp = Bm + (size_t)(bn * 128 + lr) * K + lk;
    float acc[8][8] = {};
    for (int k0 = 0; k0 < K; k0 += 16) {
        float4 a0 = *(const float4*)(Ap + k0);
        float4 a1 = *(const float4*)(Ap + k0 + 4);
        float4 b0 = *(const float4*)(Bp + k0);
        float4 b1 = *(const float4*)(Bp + k0 + 4);
        __syncthreads();
        As[lk + 0][lr] = a0.x; As[lk + 1][lr] = a0.y; As[lk + 2][lr] = a0.z; As[lk + 3][lr] = a0.w;
        As[lk + 4][lr] = a1.x; As[lk + 5][lr] = a1.y; As[lk + 6][lr] = a1.z; As[lk + 7][lr] = a1.w;
        Bs[lk + 0][lr] = b0.x; Bs[lk + 1][lr] = b0.y; Bs[lk + 2][lr] = b0.z; Bs[lk + 3][lr] = b0.w;
        Bs[lk + 4][lr] = b1.x; Bs[lk + 5][lr] = b1.y; Bs[lk + 6][lr] = b1.z; Bs[lk + 7][lr] = b1.w;
        __syncthreads();
#pragma unroll
        for (int kk = 0; kk < 16; ++kk) {
            float a[8], b[8];
            *(float4*)(a)     = *(const float4*)&As[kk][ty];
            *(float4*)(a + 4) = *(const float4*)&As[kk][ty + 4];
            *(float4*)(b)     = *(const float4*)&Bs[kk][tx];
            *(float4*)(b + 4) = *(const float4*)&Bs[kk][tx + 4];
#pragma unroll
            for (int i = 0; i < 8; ++i)
#pragma unroll
                for (int j = 0; j < 8; ++j) acc[i][j] = fmaf(a[i], b[j], acc[i][j]);
        }
    }
#pragma unroll
    for (int i = 0; i < 8; ++i) {
        int row = bm * 128 + ty + i;
#pragma unroll
        for (int j = 0; j < 8; ++j) {
            int col = bn * 128 + tx + j;
            Cd[(size_t)row * N + col] = acc[i][j] + bias[col];
        }
    }
}

// 64x64 tile GEMM helper (BK=16). Arow/Brow already offset by (lr*ld + lc).
__device__ __forceinline__ void tile64(const float* __restrict__ Arow,
                                       const float* __restrict__ Brow,
                                       int K, float acc[4][4],
                                       float* __restrict__ As,
                                       float* __restrict__ Bs)
{
    const int tid = threadIdx.x;
    const int lr = tid >> 2, lc = (tid & 3) << 2;
    const int tx = tid & 15, ty = tid >> 4;
    for (int k0 = 0; k0 < K; k0 += 16) {
        float4 av = *(const float4*)(Arow + k0);
        float4 bv = *(const float4*)(Brow + k0);
        __syncthreads();
        As[lr * 17 + lc + 0] = av.x; As[lr * 17 + lc + 1] = av.y;
        As[lr * 17 + lc + 2] = av.z; As[lr * 17 + lc + 3] = av.w;
        Bs[lr * 17 + lc + 0] = bv.x; Bs[lr * 17 + lc + 1] = bv.y;
        Bs[lr * 17 + lc + 2] = bv.z; Bs[lr * 17 + lc + 3] = bv.w;
        __syncthreads();
#pragma unroll
        for (int kk = 0; kk < 16; ++kk) {
            float a[4], b[4];
#pragma unroll
            for (int i = 0; i < 4; ++i) a[i] = As[(ty * 4 + i) * 17 + kk];
#pragma unroll
            for (int j = 0; j < 4; ++j) b[j] = Bs[(tx * 4 + j) * 17 + kk];
#pragma unroll
            for (int i = 0; i < 4; ++i)
#pragma unroll
                for (int j = 0; j < 4; ++j) acc[i][j] = fmaf(a[i], b[j], acc[i][j]);
        }
    }
    __syncthreads();   // caller may reuse LDS
}

// Split-K partials: Cpart[kz][M][N] (validated round 5).
__global__ __launch_bounds__(256) void gemm_part(
    const float* __restrict__ A, const float* __restrict__ Bm,
    float* __restrict__ Cpart, int M, int N, int K)
{
    __shared__ float smem[2176];
    const int bn = blockIdx.x, bm = blockIdx.y, kz = blockIdx.z, KS = gridDim.z;
    const int tid = threadIdx.x;
    const int lr = tid >> 2, lc = (tid & 3) << 2;
    const int tx = tid & 15, ty = tid >> 4;
    const int kLen = K / KS, k0base = kz * kLen;
    float acc[4][4] = {};
    tile64(A + (size_t)(bm * 64 + lr) * K + k0base + lc,
           Bm + (size_t)(bn * 64 + lr) * K + k0base + lc,
           kLen, acc, smem, smem + 1088);
    float* Cp = Cpart + (size_t)kz * M * N;
#pragma unroll
    for (int i = 0; i < 4; ++i) {
        int row = bm * 64 + ty * 4 + i;
#pragma unroll
        for (int j = 0; j < 4; ++j)
            Cp[(size_t)row * N + bn * 64 + tx * 4 + j] = acc[i][j];
    }
}

__global__ void reduce_partials(const float* __restrict__ Cpart, int KS,
                                const float* __restrict__ bias,
                                const float* __restrict__ bias2,
                                float* __restrict__ C, int MN, int N)
{
    int idx = blockIdx.x * 256 + threadIdx.x;
    if (idx >= MN) return;
    float v = 0.f;
    for (int z = 0; z < KS; ++z) v += Cpart[(size_t)z * MN + idx];
    int col = idx % N;
    if (bias)  v += bias[col];
    if (bias2) v += bias2[col];
    C[idx] = v;
}

__global__ void init_k(const float* __restrict__ tok_embed, float* __restrict__ cur_emb,
                       float* __restrict__ negent_acc, float* __restrict__ logp_acc)
{
    int i = blockIdx.x * 256 + threadIdx.x;
    if (i < B_ * E_) cur_emb[i] = tok_embed[i % E_];
    if (i < B_) { negent_acc[i] = 0.f; logp_acc[i] = 0.f; }
}

// ---------------------------------------------------------------------------
// Fused gates GEMM + LSTM. 64 blocks; block handles h-slice hs=blk*16 across
// all 4 gates (gate-interleaved B-columns) so the LSTM cell is block-local.
// ---------------------------------------------------------------------------
__global__ __launch_bounds__(256) void gates_lstm_k(
    const float* __restrict__ cur_emb, const float* __restrict__ W_ih,
    const float* __restrict__ hh_gates, const float* __restrict__ enc_c0,
    float* __restrict__ out_h)
{
    __shared__ float smem[4096];
    float* As = smem;
    float* Bs = smem + 1088;
    const int tid = threadIdx.x;
    const int hs = blockIdx.x * 16;
    const int lr = tid >> 2, lc = (tid & 3) << 2;
    const int tx = tid & 15, ty = tid >> 4;
    const int acol = (lr >> 4) * H_ + hs + (lr & 15);   // gate-interleaved col
    float acc[4][4] = {};
    tile64(cur_emb + (size_t)lr * E_ + lc,
           W_ih + (size_t)acol * E_ + lc, E_, acc, As, Bs);
    float* gbuf = smem;   // [64 b][64 c], c = gate*16 + w
#pragma unroll
    for (int i = 0; i < 4; ++i)
#pragma unroll
        for (int j = 0; j < 4; ++j) {
            int b = ty * 4 + i, c = tx * 4 + j;
            int col = (c >> 4) * H_ + hs + (c & 15);
            gbuf[b * 64 + c] = acc[i][j] + hh_gates[b * H4_ + col];
        }
    __syncthreads();
    for (int u = tid; u < 1024; u += 256) {
        int b = u >> 4, w = u & 15;
        float gi = gbuf[b * 64 + w],      gf = gbuf[b * 64 + 16 + w];
        float gg = gbuf[b * 64 + 32 + w], go = gbuf[b * 64 + 48 + w];
        float c0v = enc_c0[b * H_ + hs + w];
        float cc = sigm(gf) * c0v + sigm(gi) * tanhf(gg);
        out_h[b * H_ + hs + w] = sigm(go) * tanhf(cc);
    }
}

// ---------------------------------------------------------------------------
// Attention scores: 256 blocks x 4 waves = 1024 waves; wave (b, sg) does 10 s.
// dec partial-sum (KS=4) + dec_b folded in registers.
// ---------------------------------------------------------------------------
__global__ __launch_bounds__(256) void score_k(
    const float* __restrict__ enc_t, const float* __restrict__ dec_part,
    const float* __restrict__ dec_b, const float* __restrict__ attn_W,
    const float* __restrict__ attn_b, const int* __restrict__ lens,
    float* __restrict__ scores)
{
    const int lane = threadIdx.x & 63;
    const int gw = blockIdx.x * 4 + (threadIdx.x >> 6);
    const int b = gw >> 4, sg = gw & 15;
    float dec_r[16], aw_r[16];
#pragma unroll
    for (int it = 0; it < 16; ++it) {
        int h = lane + it * 64;
        dec_r[it] = dec_part[(size_t)b * H_ + h]
                  + dec_part[(size_t)(B_ + b) * H_ + h]
                  + dec_part[(size_t)(2 * B_ + b) * H_ + h]
                  + dec_part[(size_t)(3 * B_ + b) * H_ + h]
                  + dec_b[h];
        aw_r[it] = attn_W[h];
    }
    const int len = lens[b];
    const float ab = attn_b[0];
    for (int s = sg * 10; s < sg * 10 + 10; ++s) {
        if (s >= len) { if (lane == 0) scores[b * S_ + s] = -1e9f; continue; }
        const float* ep = enc_t + ((size_t)s * B_ + b) * H_;
        float acc = 0.f;
#pragma unroll
        for (int it = 0; it < 16; ++it)
            acc += aw_r[it] * tanhf(ep[lane + it * 64] + dec_r[it]);
        for (int d = 32; d; d >>= 1) acc += __shfl_xor(acc, d);
        if (lane == 0) scores[b * S_ + s] = acc + ab;
    }
}

// ---------------------------------------------------------------------------
// Softmax (redundant per b-quad) + context + attn-map output. 256 blocks.
// ---------------------------------------------------------------------------
__global__ __launch_bounds__(256) void softmax_ctx_k(
    const float* __restrict__ scores, const float* __restrict__ enc_out,
    float* __restrict__ context, float* __restrict__ out_attn, int t)
{
    __shared__ float sc[S_];
    const int tid = threadIdx.x;
    const int lane = tid & 63, wv = tid >> 6;
    const int b = blockIdx.x >> 2, hc = blockIdx.x & 3;
    if (wv == 0) {
        float m = -1e30f;
        for (int s = lane; s < S_; s += 64) {
            float v = scores[b * S_ + s]; sc[s] = v; m = fmaxf(m, v);
        }
        for (int d = 32; d; d >>= 1) m = fmaxf(m, __shfl_xor(m, d));
        float sum = 0.f;
        for (int s = lane; s < S_; s += 64) {
            float e = expf(sc[s] - m); sc[s] = e; sum += e;
        }
        for (int d = 32; d; d >>= 1) sum += __shfl_xor(sum, d);
        float inv = 1.f / sum;
        for (int s = lane; s < S_; s += 64) {
            float pr = sc[s] * inv; sc[s] = pr;
            if (hc == 0) out_attn[((size_t)b * T_ + t) * S_ + s] = pr;
        }
    }
    __syncthreads();
    const int h = hc * 256 + tid;
    float acc = 0.f;
#pragma unroll 8
    for (int s = 0; s < S_; ++s)
        acc += sc[s] * enc_out[((size_t)s * B_ + b) * H_ + h];
    context[b * H_ + h] = acc;
}

// One block per b: logits (V=64), softmax+renorm, argmax, stats, embed gather.
__global__ __launch_bounds__(256) void out_step_k(
    const float* __restrict__ context, const float* __restrict__ out_h,
    const float* __restrict__ out_W, const float* __restrict__ out_b,
    const float* __restrict__ embed, float* __restrict__ cur_emb,
    float* __restrict__ negent_acc, float* __restrict__ logp_acc,
    float* __restrict__ out_toks, int t)
{
    __shared__ float comb[2 * H_];
    __shared__ float lg[V_];
    __shared__ int tok_s;
    const int b = blockIdx.x;
    for (int i = threadIdx.x; i < H_; i += 256) {
        comb[i] = context[b * H_ + i];
        comb[H_ + i] = out_h[b * H_ + i];
    }
    __syncthreads();
    const int wave = threadIdx.x >> 6, lane = threadIdx.x & 63;
    for (int v = wave * 16; v < wave * 16 + 16; ++v) {
        float acc = 0.f;
        const float* w = out_W + (size_t)v * (2 * H_);
#pragma unroll
        for (int j = 0; j < (2 * H_) / 64; ++j)
            acc += comb[lane + j * 64] * w[lane + j * 64];
        for (int d = 32; d; d >>= 1) acc += __shfl_xor(acc, d);
        if (lane == 0) lg[v] = acc + out_b[v];
    }
    __syncthreads();
    if (wave == 0) {
        float x = lg[lane];
        float m = x;
        for (int d = 32; d; d >>= 1) m = fmaxf(m, __shfl_xor(m, d));
        float e = expf(x - m);
        float s = e;
        for (int d = 32; d; d >>= 1) s += __shfl_xor(s, d);
        float p = e / s;
        float ps = p;
        for (int d = 32; d; d >>= 1) ps += __shfl_xor(ps, d);
        p = p / ps;   // reference renormalizes
        float bv = p; int bi = lane;
        for (int d = 32; d; d >>= 1) {
            float ov = __shfl_xor(bv, d); int oi = __shfl_xor(bi, d);
            if (ov > bv || (ov == bv && oi < bi)) { bv = ov; bi = oi; }
        }
        float ne = p * logf(p + 1e-6f);
        for (int d = 32; d; d >>= 1) ne += __shfl_xor(ne, d);
        float ptok = __shfl(p, bi);
        if (lane == 0) {
            out_toks[t * B_ + b] = (float)bi;
            negent_acc[b] += ne;
            logp_acc[b] += logf(ptok + 1e-6f);
            tok_s = bi;
        }
    }
    __syncthreads();
    const int tok = tok_s;
    for (int i = threadIdx.x; i < E_; i += 256)
        cur_emb[b * E_ + i] = embed[(size_t)tok * E_ + i];
}

__global__ void final_k(const float* __restrict__ negent_acc, const float* __restrict__ logp_acc,
                        float* __restrict__ out)
{
    int b = threadIdx.x;   // 64
    out[T_ * B_ + B_ * T_ * S_ + b] = negent_acc[b];
    out[T_ * B_ + B_ * T_ * S_ + B_ + b] = logp_acc[b];
}

extern "C" void kernel_launch(void* const* d_in, const int* in_sizes, int n_in,
                              void* d_out, int out_size, void* d_ws, size_t ws_size,
                              hipStream_t stream) {
    const float* enc_h0  = (const float*)d_in[0];
    const float* enc_c0  = (const float*)d_in[1];
    const float* enc_out = (const float*)d_in[2];
    const int*   lens    = (const int*)d_in[3];
    const float* tok_emb = (const float*)d_in[4];
    const float* embed   = (const float*)d_in[5];
    const float* W_ih    = (const float*)d_in[6];
    const float* W_hh    = (const float*)d_in[7];
    const float* b_ih    = (const float*)d_in[8];
    const float* b_hh    = (const float*)d_in[9];
    const float* out_W   = (const float*)d_in[10];
    const float* out_b   = (const float*)d_in[11];
    const float* enc_W   = (const float*)d_in[12];
    const float* enc_b   = (const float*)d_in[13];
    const float* dec_W   = (const float*)d_in[14];
    const float* dec_b   = (const float*)d_in[15];
    const float* attn_W  = (const float*)d_in[16];
    const float* attn_b  = (const float*)d_in[17];
    float* out = (float*)d_out;

    // ws layout (floats). part aliases enc_t (consumed before enc_t written).
    float* ws = (float*)d_ws;
    float* hh_gates = ws;                       // 262144
    float* out_h    = hh_gates + B_ * H4_;      // 65536
    float* dec_part = out_h + B_ * H_;          // 262144 (4 x B x H)
    float* scores   = dec_part + 4 * B_ * H_;   // 10240
    float* context  = scores + B_ * S_;         // 65536
    float* negent   = context + B_ * H_;        // 64
    float* logp     = negent + B_;              // 64
    float* cur_emb  = logp + B_;                // 32768
    float* enc_t    = cur_emb + B_ * E_;        // 10485760
    float* part     = enc_t;                    // alias: 4 x B x 4H = 1048576
    // total = 11,184,256 floats = 44,737,024 B (ws_size known >= 49,152,512)
    if (ws_size < 44737024u) return;

    init_k<<<(B_ * E_ + 255) / 256, 256, 0, stream>>>(tok_emb, cur_emb, negent, logp);

    // hh_gates = h0 @ W_hh^T + b_ih + b_hh (step-invariant)
    gemm_part<<<dim3(H4_ / 64, 1, 4), 256, 0, stream>>>(enc_h0, W_hh, part, B_, H4_, H_);
    reduce_partials<<<(B_ * H4_ + 255) / 256, 256, 0, stream>>>(
        part, 4, b_ih, b_hh, hh_gates, B_ * H4_, H4_);

    // enc_t = encoder_outputs @ enc_W^T + enc_b (after part consumed)
    gemm_bt_128<<<dim3(H_ / 128, (S_ * B_) / 128), 256, 0, stream>>>(
        enc_out, enc_W, enc_b, enc_t, S_ * B_, H_, H_);

    for (int t = 0; t < T_; ++t) {
        gates_lstm_k<<<64, 256, 0, stream>>>(cur_emb, W_ih, hh_gates, enc_c0, out_h);
        gemm_part<<<dim3(H_ / 64, 1, 4), 256, 0, stream>>>(out_h, dec_W, dec_part, B_, H_, H_);
        score_k<<<256, 256, 0, stream>>>(enc_t, dec_part, dec_b, attn_W, attn_b, lens, scores);
        softmax_ctx_k<<<256, 256, 0, stream>>>(scores, enc_out, context, out + T_ * B_, t);
        out_step_k<<<64, 256, 0, stream>>>(context, out_h, out_W, out_b, embed, cur_emb,
                                           negent, logp, out, t);
    }
    final_k<<<1, B_, 0, stream>>>(negent, logp, out);
}

// Round 8
// 1870.812 us; speedup vs baseline: 2.8458x; 1.4259x over previous
//
#include <hip/hip_runtime.h>

#define S_ 160
#define B_ 64
#define H_ 1024
#define E_ 512
#define V_ 64
#define T_ 16
#define H4_ 4096

__device__ __forceinline__ float sigm(float x) { return 1.f / (1.f + expf(-x)); }

// ---------------------------------------------------------------------------
// enc_t = enc_out @ enc_W^T + enc_b.  128x128 tile, BK=16, 8x8 acc/thread.
// Fragments split at stride 64 (cols tx4..tx4+3 and 64+tx4..): LDS reads are
// 2-way bank aliases (free) instead of the old 4-way conflict.
// ---------------------------------------------------------------------------
__global__ __launch_bounds__(256) void gemm_bt_128(
    const float* __restrict__ A, const float* __restrict__ Bm,
    const float* __restrict__ bias, float* __restrict__ Cd,
    int M, int N, int K)
{
    __shared__ float As[16][132];
    __shared__ float Bs[16][132];
    const int bn = blockIdx.x, bm = blockIdx.y;
    const int tid = threadIdx.x;
    const int lr = tid >> 1, lk = (tid & 1) * 8;
    const int tx4 = (tid & 15) * 4, ty4 = (tid >> 4) * 4;
    const float* Ap = A + (size_t)(bm * 128 + lr) * K + lk;
    const float* Bp = Bm + (size_t)(bn * 128 + lr) * K + lk;
    float acc[8][8] = {};
    for (int k0 = 0; k0 < K; k0 += 16) {
        float4 a0 = *(const float4*)(Ap + k0);
        float4 a1 = *(const float4*)(Ap + k0 + 4);
        float4 b0 = *(const float4*)(Bp + k0);
        float4 b1 = *(const float4*)(Bp + k0 + 4);
        __syncthreads();
        As[lk + 0][lr] = a0.x; As[lk + 1][lr] = a0.y; As[lk + 2][lr] = a0.z; As[lk + 3][lr] = a0.w;
        As[lk + 4][lr] = a1.x; As[lk + 5][lr] = a1.y; As[lk + 6][lr] = a1.z; As[lk + 7][lr] = a1.w;
        Bs[lk + 0][lr] = b0.x; Bs[lk + 1][lr] = b0.y; Bs[lk + 2][lr] = b0.z; Bs[lk + 3][lr] = b0.w;
        Bs[lk + 4][lr] = b1.x; Bs[lk + 5][lr] = b1.y; Bs[lk + 6][lr] = b1.z; Bs[lk + 7][lr] = b1.w;
        __syncthreads();
#pragma unroll
        for (int kk = 0; kk < 16; ++kk) {
            float a[8], b[8];
            *(float4*)(a)     = *(const float4*)&As[kk][ty4];
            *(float4*)(a + 4) = *(const float4*)&As[kk][64 + ty4];
            *(float4*)(b)     = *(const float4*)&Bs[kk][tx4];
            *(float4*)(b + 4) = *(const float4*)&Bs[kk][64 + tx4];
#pragma unroll
            for (int i = 0; i < 8; ++i)
#pragma unroll
                for (int j = 0; j < 8; ++j) acc[i][j] = fmaf(a[i], b[j], acc[i][j]);
        }
    }
#pragma unroll
    for (int i = 0; i < 8; ++i) {
        int row = bm * 128 + ((i < 4) ? (ty4 + i) : (64 + ty4 + i - 4));
#pragma unroll
        for (int j = 0; j < 8; ++j) {
            int col = bn * 128 + ((j < 4) ? (tx4 + j) : (64 + tx4 + j - 4));
            Cd[(size_t)row * N + col] = acc[i][j] + bias[col];
        }
    }
}

// 64x64 tile GEMM helper (BK=16). Arow/Brow already offset by (lr*ld + lc).
__device__ __forceinline__ void tile64(const float* __restrict__ Arow,
                                       const float* __restrict__ Brow,
                                       int K, float acc[4][4],
                                       float* __restrict__ As,
                                       float* __restrict__ Bs)
{
    const int tid = threadIdx.x;
    const int lr = tid >> 2, lc = (tid & 3) << 2;
    const int tx = tid & 15, ty = tid >> 4;
    for (int k0 = 0; k0 < K; k0 += 16) {
        float4 av = *(const float4*)(Arow + k0);
        float4 bv = *(const float4*)(Brow + k0);
        __syncthreads();
        As[lr * 17 + lc + 0] = av.x; As[lr * 17 + lc + 1] = av.y;
        As[lr * 17 + lc + 2] = av.z; As[lr * 17 + lc + 3] = av.w;
        Bs[lr * 17 + lc + 0] = bv.x; Bs[lr * 17 + lc + 1] = bv.y;
        Bs[lr * 17 + lc + 2] = bv.z; Bs[lr * 17 + lc + 3] = bv.w;
        __syncthreads();
#pragma unroll
        for (int kk = 0; kk < 16; ++kk) {
            float a[4], b[4];
#pragma unroll
            for (int i = 0; i < 4; ++i) a[i] = As[(ty * 4 + i) * 17 + kk];
#pragma unroll
            for (int j = 0; j < 4; ++j) b[j] = Bs[(tx * 4 + j) * 17 + kk];
#pragma unroll
            for (int i = 0; i < 4; ++i)
#pragma unroll
                for (int j = 0; j < 4; ++j) acc[i][j] = fmaf(a[i], b[j], acc[i][j]);
        }
    }
    __syncthreads();
}

// Split-K partials: Cpart[kz][M][N] (validated).
__global__ __launch_bounds__(256) void gemm_part(
    const float* __restrict__ A, const float* __restrict__ Bm,
    float* __restrict__ Cpart, int M, int N, int K)
{
    __shared__ float smem[2176];
    const int bn = blockIdx.x, bm = blockIdx.y, kz = blockIdx.z, KS = gridDim.z;
    const int tid = threadIdx.x;
    const int lr = tid >> 2, lc = (tid & 3) << 2;
    const int tx = tid & 15, ty = tid >> 4;
    const int kLen = K / KS, k0base = kz * kLen;
    float acc[4][4] = {};
    tile64(A + (size_t)(bm * 64 + lr) * K + k0base + lc,
           Bm + (size_t)(bn * 64 + lr) * K + k0base + lc,
           kLen, acc, smem, smem + 1088);
    float* Cp = Cpart + (size_t)kz * M * N;
#pragma unroll
    for (int i = 0; i < 4; ++i) {
        int row = bm * 64 + ty * 4 + i;
#pragma unroll
        for (int j = 0; j < 4; ++j)
            Cp[(size_t)row * N + bn * 64 + tx * 4 + j] = acc[i][j];
    }
}

__global__ void reduce_partials(const float* __restrict__ Cpart, int KS,
                                const float* __restrict__ bias,
                                const float* __restrict__ bias2,
                                float* __restrict__ C, int MN, int N)
{
    int idx = blockIdx.x * 256 + threadIdx.x;
    if (idx >= MN) return;
    float v = 0.f;
    for (int z = 0; z < KS; ++z) v += Cpart[(size_t)z * MN + idx];
    int col = idx % N;
    if (bias)  v += bias[col];
    if (bias2) v += bias2[col];
    C[idx] = v;
}

__global__ void init_k(const float* __restrict__ tok_embed, float* __restrict__ cur_emb,
                       float* __restrict__ negent_acc, float* __restrict__ logp_acc)
{
    int i = blockIdx.x * 256 + threadIdx.x;
    if (i < B_ * E_) cur_emb[i] = tok_embed[i % E_];
    if (i < B_) { negent_acc[i] = 0.f; logp_acc[i] = 0.f; }
}

// ---------------------------------------------------------------------------
// Fused gates GEMM + LSTM, 256 blocks. Block bn covers 4 h-values
// (hs4 = bn*4) across all 4 gates: a 64(b) x 16(col) tile, K = E = 512.
// col c = g*4 + w  ->  global W_ih row (g*H + hs4 + w). LSTM is block-local.
// ---------------------------------------------------------------------------
__global__ __launch_bounds__(256) void gates_lstm_k(
    const float* __restrict__ cur_emb, const float* __restrict__ W_ih,
    const float* __restrict__ hh_gates, const float* __restrict__ enc_c0,
    float* __restrict__ out_h)
{
    __shared__ float As[16][68];    // [k][row]
    __shared__ float Bs[16][17];    // [k][col]
    __shared__ float gbuf[64][17];  // [row][col]
    const int tid = threadIdx.x;
    const int hs4 = blockIdx.x * 4;
    const int c = tid & 15, rq = tid >> 4;        // compute mapping
    const int colg = (c >> 2) * H_ + hs4 + (c & 3);
    const int kk_s = tid & 15, cs = tid >> 4;     // staging mapping
    const int colg_s = (cs >> 2) * H_ + hs4 + (cs & 3);
    float acc[4] = {};
    for (int k0 = 0; k0 < E_; k0 += 16) {
        float a0 = cur_emb[(size_t)(cs     ) * E_ + k0 + kk_s];
        float a1 = cur_emb[(size_t)(cs + 16) * E_ + k0 + kk_s];
        float a2 = cur_emb[(size_t)(cs + 32) * E_ + k0 + kk_s];
        float a3 = cur_emb[(size_t)(cs + 48) * E_ + k0 + kk_s];
        float bv = W_ih[(size_t)colg_s * E_ + k0 + kk_s];
        __syncthreads();
        As[kk_s][cs] = a0; As[kk_s][cs + 16] = a1;
        As[kk_s][cs + 32] = a2; As[kk_s][cs + 48] = a3;
        Bs[kk_s][cs] = bv;
        __syncthreads();
#pragma unroll
        for (int kk = 0; kk < 16; ++kk) {
            float4 a4 = *(const float4*)&As[kk][rq * 4];
            float b = Bs[kk][c];
            acc[0] = fmaf(a4.x, b, acc[0]);
            acc[1] = fmaf(a4.y, b, acc[1]);
            acc[2] = fmaf(a4.z, b, acc[2]);
            acc[3] = fmaf(a4.w, b, acc[3]);
        }
    }
    __syncthreads();
#pragma unroll
    for (int i = 0; i < 4; ++i)
        gbuf[rq * 4 + i][c] = acc[i] + hh_gates[(size_t)(rq * 4 + i) * H4_ + colg];
    __syncthreads();
    const int row = tid >> 2, w2 = tid & 3;
    float gi = gbuf[row][0 + w2], gf = gbuf[row][4 + w2];
    float gg = gbuf[row][8 + w2], go = gbuf[row][12 + w2];
    float c0v = enc_c0[(size_t)row * H_ + hs4 + w2];
    float cc = sigm(gf) * c0v + sigm(gi) * tanhf(gg);
    out_h[(size_t)row * H_ + hs4 + w2] = sigm(go) * tanhf(cc);
}

// ---------------------------------------------------------------------------
// Attention scores: 512 blocks x 4 waves = 2048 waves; wave (b, sg) does 5 s.
// dec partial-sum (KS=4) + dec_b folded in registers.
// ---------------------------------------------------------------------------
__global__ __launch_bounds__(256) void score_k(
    const float* __restrict__ enc_t, const float* __restrict__ dec_part,
    const float* __restrict__ dec_b, const float* __restrict__ attn_W,
    const float* __restrict__ attn_b, const int* __restrict__ lens,
    float* __restrict__ scores)
{
    const int lane = threadIdx.x & 63;
    const int gw = blockIdx.x * 4 + (threadIdx.x >> 6);   // 0..2047
    const int b = gw >> 5, sg = gw & 31;                  // 32 waves/b, 5 s each
    float dec_r[16], aw_r[16];
#pragma unroll
    for (int it = 0; it < 16; ++it) {
        int h = lane + it * 64;
        dec_r[it] = dec_part[(size_t)b * H_ + h]
                  + dec_part[(size_t)(B_ + b) * H_ + h]
                  + dec_part[(size_t)(2 * B_ + b) * H_ + h]
                  + dec_part[(size_t)(3 * B_ + b) * H_ + h]
                  + dec_b[h];
        aw_r[it] = attn_W[h];
    }
    const int len = lens[b];
    const float ab = attn_b[0];
    for (int s = sg * 5; s < sg * 5 + 5; ++s) {
        if (s >= len) { if (lane == 0) scores[b * S_ + s] = -1e9f; continue; }
        const float* ep = enc_t + ((size_t)s * B_ + b) * H_;
        float acc = 0.f;
#pragma unroll
        for (int it = 0; it < 16; ++it)
            acc += aw_r[it] * tanhf(ep[lane + it * 64] + dec_r[it]);
        for (int d = 32; d; d >>= 1) acc += __shfl_xor(acc, d);
        if (lane == 0) scores[b * S_ + s] = acc + ab;
    }
}

// ---------------------------------------------------------------------------
// Fused: softmax + attn-map out + context (float4, 4-acc ILP) + logits +
// softmax/renorm + argmax + stats + next-embedding gather. One block per b.
// ---------------------------------------------------------------------------
__global__ __launch_bounds__(256) void smax_out_k(
    const float* __restrict__ scores, const float* __restrict__ enc_out,
    const float* __restrict__ out_h, const float* __restrict__ out_W,
    const float* __restrict__ out_b, const float* __restrict__ embed,
    float* __restrict__ cur_emb, float* __restrict__ negent_acc,
    float* __restrict__ logp_acc, float* __restrict__ out, int t)
{
    __shared__ float sc[S_];
    __shared__ float comb[2 * H_];
    __shared__ float lg[V_];
    __shared__ int tok_s;
    const int tid = threadIdx.x;
    const int b = blockIdx.x;
    const int lane = tid & 63, wv = tid >> 6;
    if (wv == 0) {
        float m = -1e30f;
        for (int s = lane; s < S_; s += 64) {
            float v = scores[b * S_ + s]; sc[s] = v; m = fmaxf(m, v);
        }
        for (int d = 32; d; d >>= 1) m = fmaxf(m, __shfl_xor(m, d));
        float sum = 0.f;
        for (int s = lane; s < S_; s += 64) {
            float e = expf(sc[s] - m); sc[s] = e; sum += e;
        }
        for (int d = 32; d; d >>= 1) sum += __shfl_xor(sum, d);
        float inv = 1.f / sum;
        for (int s = lane; s < S_; s += 64) {
            float pr = sc[s] * inv; sc[s] = pr;
            out[T_ * B_ + ((size_t)b * T_ + t) * S_ + s] = pr;
        }
    }
    __syncthreads();
    // context: thread handles 4 h via float4; 4 independent accumulators.
    {
        const float* base = enc_out + (size_t)b * H_ + tid * 4;
        float4 ac0 = {0,0,0,0}, ac1 = {0,0,0,0}, ac2 = {0,0,0,0}, ac3 = {0,0,0,0};
#pragma unroll 4
        for (int s = 0; s < S_; s += 4) {
            float4 e0 = *(const float4*)(base + (size_t)(s    ) * B_ * H_);
            float4 e1 = *(const float4*)(base + (size_t)(s + 1) * B_ * H_);
            float4 e2 = *(const float4*)(base + (size_t)(s + 2) * B_ * H_);
            float4 e3 = *(const float4*)(base + (size_t)(s + 3) * B_ * H_);
            float p0 = sc[s], p1 = sc[s + 1], p2 = sc[s + 2], p3 = sc[s + 3];
            ac0.x = fmaf(p0, e0.x, ac0.x); ac0.y = fmaf(p0, e0.y, ac0.y);
            ac0.z = fmaf(p0, e0.z, ac0.z); ac0.w = fmaf(p0, e0.w, ac0.w);
            ac1.x = fmaf(p1, e1.x, ac1.x); ac1.y = fmaf(p1, e1.y, ac1.y);
            ac1.z = fmaf(p1, e1.z, ac1.z); ac1.w = fmaf(p1, e1.w, ac1.w);
            ac2.x = fmaf(p2, e2.x, ac2.x); ac2.y = fmaf(p2, e2.y, ac2.y);
            ac2.z = fmaf(p2, e2.z, ac2.z); ac2.w = fmaf(p2, e2.w, ac2.w);
            ac3.x = fmaf(p3, e3.x, ac3.x); ac3.y = fmaf(p3, e3.y, ac3.y);
            ac3.z = fmaf(p3, e3.z, ac3.z); ac3.w = fmaf(p3, e3.w, ac3.w);
        }
        comb[tid * 4 + 0] = ac0.x + ac1.x + ac2.x + ac3.x;
        comb[tid * 4 + 1] = ac0.y + ac1.y + ac2.y + ac3.y;
        comb[tid * 4 + 2] = ac0.z + ac1.z + ac2.z + ac3.z;
        comb[tid * 4 + 3] = ac0.w + ac1.w + ac2.w + ac3.w;
    }
    for (int i = tid; i < H_; i += 256) comb[H_ + i] = out_h[(size_t)b * H_ + i];
    __syncthreads();
    for (int v = wv * 16; v < wv * 16 + 16; ++v) {
        const float* w = out_W + (size_t)v * (2 * H_);
        float a0 = 0.f, a1 = 0.f;
#pragma unroll
        for (int j = 0; j < 32; j += 2) {
            a0 = fmaf(comb[lane + j * 64], w[lane + j * 64], a0);
            a1 = fmaf(comb[lane + (j + 1) * 64], w[lane + (j + 1) * 64], a1);
        }
        float acc = a0 + a1;
        for (int d = 32; d; d >>= 1) acc += __shfl_xor(acc, d);
        if (lane == 0) lg[v] = acc + out_b[v];
    }
    __syncthreads();
    if (wv == 0) {
        float x = lg[lane];
        float m = x;
        for (int d = 32; d; d >>= 1) m = fmaxf(m, __shfl_xor(m, d));
        float e = expf(x - m);
        float s = e;
        for (int d = 32; d; d >>= 1) s += __shfl_xor(s, d);
        float p = e / s;
        float ps = p;
        for (int d = 32; d; d >>= 1) ps += __shfl_xor(ps, d);
        p = p / ps;   // reference renormalizes
        float bv = p; int bi = lane;
        for (int d = 32; d; d >>= 1) {
            float ov = __shfl_xor(bv, d); int oi = __shfl_xor(bi, d);
            if (ov > bv || (ov == bv && oi < bi)) { bv = ov; bi = oi; }
        }
        float ne = p * logf(p + 1e-6f);
        for (int d = 32; d; d >>= 1) ne += __shfl_xor(ne, d);
        float ptok = __shfl(p, bi);
        if (lane == 0) {
            out[t * B_ + b] = (float)bi;
            float na = negent_acc[b] + ne;                negent_acc[b] = na;
            float la = logp_acc[b] + logf(ptok + 1e-6f);  logp_acc[b] = la;
            if (t == T_ - 1) {
                out[T_ * B_ + B_ * T_ * S_ + b] = na;
                out[T_ * B_ + B_ * T_ * S_ + B_ + b] = la;
            }
            tok_s = bi;
        }
    }
    __syncthreads();
    const int tok = tok_s;
    for (int i = tid; i < E_; i += 256)
        cur_emb[(size_t)b * E_ + i] = embed[(size_t)tok * E_ + i];
}

extern "C" void kernel_launch(void* const* d_in, const int* in_sizes, int n_in,
                              void* d_out, int out_size, void* d_ws, size_t ws_size,
                              hipStream_t stream) {
    const float* enc_h0  = (const float*)d_in[0];
    const float* enc_c0  = (const float*)d_in[1];
    const float* enc_out = (const float*)d_in[2];
    const int*   lens    = (const int*)d_in[3];
    const float* tok_emb = (const float*)d_in[4];
    const float* embed   = (const float*)d_in[5];
    const float* W_ih    = (const float*)d_in[6];
    const float* W_hh    = (const float*)d_in[7];
    const float* b_ih    = (const float*)d_in[8];
    const float* b_hh    = (const float*)d_in[9];
    const float* out_W   = (const float*)d_in[10];
    const float* out_b   = (const float*)d_in[11];
    const float* enc_W   = (const float*)d_in[12];
    const float* enc_b   = (const float*)d_in[13];
    const float* dec_W   = (const float*)d_in[14];
    const float* dec_b   = (const float*)d_in[15];
    const float* attn_W  = (const float*)d_in[16];
    const float* attn_b  = (const float*)d_in[17];
    float* out = (float*)d_out;

    // ws layout (floats). part aliases enc_t (consumed before enc_t written).
    float* ws = (float*)d_ws;
    float* hh_gates = ws;                       // 262144
    float* out_h    = hh_gates + B_ * H4_;      // 65536
    float* dec_part = out_h + B_ * H_;          // 262144 (4 x B x H)
    float* scores   = dec_part + 4 * B_ * H_;   // 10240
    float* negent   = scores + B_ * S_;         // 64
    float* logp     = negent + B_;              // 64
    float* cur_emb  = logp + B_;                // 32768
    float* enc_t    = cur_emb + B_ * E_;        // 10485760
    float* part     = enc_t;                    // alias: 4 x B x 4H = 1048576
    // total = 11,118,720 floats = 44,474,880 B (ws_size known >= 49,152,512)
    if (ws_size < 44474880u) return;

    init_k<<<(B_ * E_ + 255) / 256, 256, 0, stream>>>(tok_emb, cur_emb, negent, logp);

    // hh_gates = h0 @ W_hh^T + b_ih + b_hh (step-invariant)
    gemm_part<<<dim3(H4_ / 64, 1, 4), 256, 0, stream>>>(enc_h0, W_hh, part, B_, H4_, H_);
    reduce_partials<<<(B_ * H4_ + 255) / 256, 256, 0, stream>>>(
        part, 4, b_ih, b_hh, hh_gates, B_ * H4_, H4_);

    // enc_t = encoder_outputs @ enc_W^T + enc_b (after part consumed)
    gemm_bt_128<<<dim3(H_ / 128, (S_ * B_) / 128), 256, 0, stream>>>(
        enc_out, enc_W, enc_b, enc_t, S_ * B_, H_, H_);

    for (int t = 0; t < T_; ++t) {
        gates_lstm_k<<<256, 256, 0, stream>>>(cur_emb, W_ih, hh_gates, enc_c0, out_h);
        gemm_part<<<dim3(H_ / 64, 1, 4), 256, 0, stream>>>(out_h, dec_W, dec_part, B_, H_, H_);
        score_k<<<512, 256, 0, stream>>>(enc_t, dec_part, dec_b, attn_W, attn_b, lens, scores);
        smax_out_k<<<64, 256, 0, stream>>>(scores, enc_out, out_h, out_W, out_b, embed,
                                           cur_emb, negent, logp, out, t);
    }
}